// Round 1
// baseline (323.481 us; speedup 1.0000x reference)
//
#include <hip/hip_runtime.h>
#include <math.h>

// Problem constants (from reference)
constexpr int N = 50000, E = 800000, F = 512, P = 128, G = 256, H = 256, T = 24;
// Capacity caps (expected: ~16 edges->target, ~290 2-hop edges, ~300 nodes)
constexpr int CAPA = 4096, CAPB = 32768, CAPP = 2048, CAPH = 512;

// Workspace layout (bytes)
constexpr size_t OFF_DEG   = 0;         // float[N]
constexpr size_t OFF_CNT   = 200704;    // int[16]: 0=cntA,1=cntB,2=cntP,3=cntH,4=sync
constexpr size_t OFF_FH1   = 200768;    // uchar[N]
constexpr size_t OFF_FP    = 250880;    // uchar[N]
constexpr size_t ZERO_END  = 301056;    // memset [0, ZERO_END)
constexpr size_t OFF_IDXP  = 301056;    // int[N]
constexpr size_t OFF_IDXH1 = 501760;    // int[N]
constexpr size_t OFF_SRCA  = 702464;    // int[CAPA]
constexpr size_t OFF_WA    = 718848;    // float[CAPA]
constexpr size_t OFF_SRCB  = 735232;    // int[CAPB]
constexpr size_t OFF_DSTB  = 866304;    // int[CAPB]
constexpr size_t OFF_WB    = 997376;    // float[CAPB]
constexpr size_t OFF_LISTP = 1128448;   // int[CAPP]
constexpr size_t OFF_LISTH = 1136640;   // int[CAPH]
constexpr size_t OFF_Q     = 1138688;   // float[CAPP*G]
constexpr size_t OFF_H1S   = 3235840;   // float[CAPH*G]
constexpr size_t OFF_RS    = 3760128;   // float[CAPH*G]
constexpr size_t OFF_EMB   = 4284416;   // float[2G]
constexpr size_t OFF_SEQ   = 4286464;   // float[T*2G]
constexpr size_t OFF_XPROJ = 4335616;   // float[T*4H]
constexpr size_t OFF_RNN   = 4433920;   // float[T*H]

__device__ __forceinline__ float sigmoidf_(float x) { return 1.0f / (1.0f + expf(-x)); }

// Pass 1: degree accumulation + collect edges whose dst == target; flag 1-hop srcs.
__global__ void k_deg_scan(const int* __restrict__ ei, const float* __restrict__ eg,
                           const int* __restrict__ ptgt, float* __restrict__ deg,
                           int* __restrict__ cnt, unsigned char* __restrict__ fH1,
                           int* __restrict__ srcA, float* __restrict__ wA) {
    int target = *ptgt;
    int e = blockIdx.x * 256 + threadIdx.x;
    if (e < E) {
        int d = ei[E + e];
        float w = eg[e];
        atomicAdd(&deg[d], w);
        if (d == target) {
            int s = ei[e];
            int slot = atomicAdd(&cnt[0], 1);
            if (slot < CAPA) { srcA[slot] = s; wA[slot] = w; }
            fH1[s] = 1;
        }
    }
    if (blockIdx.x == 0 && threadIdx.x == 0) fH1[target] = 1;
}

// Pass 2: collect edges whose dst is a needed-h1 node; flag their srcs as needing p/q.
__global__ void k_scan2(const int* __restrict__ ei, const float* __restrict__ eg,
                        const unsigned char* __restrict__ fH1, unsigned char* __restrict__ fP,
                        int* __restrict__ cnt, int* __restrict__ srcB,
                        int* __restrict__ dstB, float* __restrict__ wB) {
    int e = blockIdx.x * 256 + threadIdx.x;
    if (e >= E) return;
    int d = ei[E + e];
    if (fH1[d]) {
        int s = ei[e];
        float w = eg[e];
        int slot = atomicAdd(&cnt[1], 1);
        if (slot < CAPB) { srcB[slot] = s; dstB[slot] = d; wB[slot] = w; }
        fP[s] = 1;
    }
}

// Compact flagged node sets into lists with index maps.
__global__ void k_compact(const unsigned char* __restrict__ fH1, const unsigned char* __restrict__ fP,
                          int* __restrict__ cnt, int* __restrict__ listP, int* __restrict__ listH,
                          int* __restrict__ idxP, int* __restrict__ idxH1) {
    int n = blockIdx.x * 256 + threadIdx.x;
    if (n >= N) return;
    if (fH1[n]) {
        int sh = atomicAdd(&cnt[3], 1);
        if (sh < CAPH) listH[sh] = n;
        idxH1[n] = sh;
    }
    if (fP[n] || fH1[n]) {
        int sp = atomicAdd(&cnt[2], 1);
        if (sp < CAPP) listP[sp] = n;
        idxP[n] = sp;
    }
}

// q[n] = relu((x[n]*feat_gate) @ W_proj + b_proj) @ W_g1   for needed nodes only.
__global__ void k_pq(const float* __restrict__ x, const float* __restrict__ fgate,
                     const float* __restrict__ Wproj, const float* __restrict__ bproj,
                     const float* __restrict__ Wg1, const int* __restrict__ cnt,
                     const int* __restrict__ listP, float* __restrict__ q) {
    __shared__ float xm[F];
    __shared__ float pv[P];
    int b = blockIdx.x;
    int nP = min(cnt[2], CAPP);
    if (b >= nP) return;
    int n = listP[b];
    int tid = threadIdx.x;  // 128 threads
    for (int k = tid; k < F; k += 128) xm[k] = x[(size_t)n * F + k] * fgate[k];
    __syncthreads();
    float acc = bproj[tid];
    #pragma unroll 8
    for (int k = 0; k < F; k++) acc += xm[k] * Wproj[k * P + tid];
    pv[tid] = fmaxf(acc, 0.0f);
    __syncthreads();
    for (int g = tid; g < G; g += 128) {
        float a = 0.0f;
        #pragma unroll 8
        for (int k = 0; k < P; k++) a += pv[k] * Wg1[k * G + g];
        q[(size_t)b * G + g] = a;
    }
}

// h1 for 1-hop-set nodes, then r = h1 @ W_g2. Also capture h1[target] -> emb[0:256].
__global__ void k_h1(const int* __restrict__ ptgt, const float* __restrict__ deg,
                     const int* __restrict__ cnt, const int* __restrict__ listH,
                     const int* __restrict__ idxP, const int* __restrict__ srcB,
                     const int* __restrict__ dstB, const float* __restrict__ wB,
                     const float* __restrict__ q, const float* __restrict__ bg1,
                     const float* __restrict__ Wg2, float* __restrict__ h1s,
                     float* __restrict__ rs, float* __restrict__ emb) {
    __shared__ float h1row[G];
    int b = blockIdx.x;
    int nH = min(cnt[3], CAPH);
    if (b >= nH) return;
    int n = listH[b];
    int target = *ptgt;
    int g = threadIdx.x;  // 256 threads
    float dn = 1.0f / sqrtf(deg[n] + 1.0f);
    float acc = bg1[g] + q[(size_t)idxP[n] * G + g] * dn * dn;
    int nB = min(cnt[1], CAPB);
    for (int e = 0; e < nB; e++) {
        if (dstB[e] == n) {
            int s = srcB[e];
            float nm = (1.0f / sqrtf(deg[s] + 1.0f)) * wB[e] * dn;
            acc += nm * q[(size_t)idxP[s] * G + g];
        }
    }
    float hv = fmaxf(acc, 0.0f);
    h1row[g] = hv;
    h1s[(size_t)b * G + g] = hv;
    if (n == target) emb[g] = hv;
    __syncthreads();
    float r = 0.0f;
    #pragma unroll 8
    for (int k = 0; k < G; k++) r += h1row[k] * Wg2[k * G + g];
    rs[(size_t)b * G + g] = r;
}

// h2[target], emb[256:512], and build seq (cached_gcn with row explain_pos replaced).
__global__ void k_h2_seq(const int* __restrict__ ptgt, const int* __restrict__ pepos,
                         const float* __restrict__ deg, const int* __restrict__ cnt,
                         const int* __restrict__ idxH1, const int* __restrict__ srcA,
                         const float* __restrict__ wA, const float* __restrict__ rs,
                         const float* __restrict__ bg2, const float* __restrict__ cached,
                         float* __restrict__ emb, float* __restrict__ seq) {
    int target = *ptgt;
    int epos = *pepos;
    int g = threadIdx.x;  // 256 threads
    float dt = 1.0f / sqrtf(deg[target] + 1.0f);
    int it = idxH1[target];
    float acc = bg2[g] + rs[(size_t)it * G + g] * dt * dt;
    int nA = min(cnt[0], CAPA);
    for (int e = 0; e < nA; e++) {
        int s = srcA[e];
        acc += (1.0f / sqrtf(deg[s] + 1.0f)) * wA[e] * dt * rs[(size_t)idxH1[s] * G + g];
    }
    emb[G + g] = fmaxf(acc, 0.0f);
    __syncthreads();
    for (int i = g; i < T * 2 * G; i += 256) {
        int t = i >> 9, k = i & 511;
        seq[i] = (t == epos) ? emb[k] : cached[i];
    }
}

// xproj[t][j] = seq[t] @ W_ih[:,j] + b_ih[j] + b_hh[j]  (parallel over all t)
__global__ void k_xproj(const float* __restrict__ seq, const float* __restrict__ Wih,
                        const float* __restrict__ bih, const float* __restrict__ bhh,
                        float* __restrict__ xproj) {
    __shared__ float s[2 * G];
    int t = blockIdx.x;
    int j = threadIdx.x;  // 1024 threads
    if (j < 2 * G) s[j] = seq[t * 2 * G + j];
    __syncthreads();
    float acc = bih[j] + bhh[j];
    #pragma unroll 8
    for (int k = 0; k < 2 * G; k++) acc += s[k] * Wih[k * 4 * H + j];
    xproj[t * 4 * H + j] = acc;
}

// Sequential LSTM distributed over 32 WGs (each owns 8 hidden channels, W_hh slice in LDS),
// device-scope atomic barrier per step. WG0 finishes with attention + MLP tail.
__global__ __launch_bounds__(64) void k_lstm(
        const float* __restrict__ Whh, const float* __restrict__ xproj,
        float* __restrict__ rnn, int* __restrict__ sync,
        const float* __restrict__ Watt, const float* __restrict__ batt,
        const float* __restrict__ Wp1, const float* __restrict__ bp1,
        const float* __restrict__ Wp2, const float* __restrict__ bp2,
        float* __restrict__ out) {
    __shared__ float Wl[H * 32];   // 32KB: this WG's 32 gate columns
    __shared__ float hbuf[H];
    __shared__ float part[64];
    __shared__ float gt[32];
    __shared__ float cst[8];
    __shared__ float sc[T];
    __shared__ float attw[T];
    __shared__ float ctx[H];
    __shared__ float hid[64];

    int w = blockIdx.x;            // 0..31
    int tid = threadIdx.x;         // 64 threads = 1 wave
    int c = tid & 31;              // local column 0..31
    int kh = tid >> 5;             // k-half 0/1
    // local col c -> gate (c>>3), hidden (w*8 + (c&7)) -> global col:
    int colg = (c >> 3) * H + w * 8 + (c & 7);

    // Load W_hh slice: Wl[k][c] (row-major by k, 32 cols -> conflict-free)
    for (int i = tid; i < H * 32; i += 64) {
        int k = i >> 5, cc = i & 31;
        int cg = (cc >> 3) * H + w * 8 + (cc & 7);
        Wl[i] = Whh[k * 4 * H + cg];
    }
    for (int i = tid; i < H; i += 64) hbuf[i] = 0.0f;
    if (tid < 8) cst[tid] = 0.0f;
    __syncthreads();

    for (int t = 0; t < T; t++) {
        // partial matvec: this half-wave covers k in [kh*128, kh*128+128)
        float a = 0.0f;
        int k0 = kh * 128;
        #pragma unroll 8
        for (int k = 0; k < 128; k++) a += hbuf[k0 + k] * Wl[(k0 + k) * 32 + c];
        part[tid] = a;
        __syncthreads();
        if (tid < 32) gt[tid] = part[tid] + part[tid + 32] + xproj[t * 4 * H + colg];
        __syncthreads();
        if (tid < 8) {
            float ig = sigmoidf_(gt[tid]);
            float fg = sigmoidf_(gt[8 + tid]);
            float gg = tanhf(gt[16 + tid]);
            float og = sigmoidf_(gt[24 + tid]);
            float cc = fg * cst[tid] + ig * gg;
            cst[tid] = cc;
            rnn[t * H + w * 8 + tid] = og * tanhf(cc);
        }
        __syncthreads();
        if (tid == 0) {
            __hip_atomic_fetch_add(sync, 1, __ATOMIC_RELEASE, __HIP_MEMORY_SCOPE_AGENT);
            int tgtc = 32 * (t + 1);
            while (__hip_atomic_load(sync, __ATOMIC_ACQUIRE, __HIP_MEMORY_SCOPE_AGENT) < tgtc) {
                __builtin_amdgcn_s_sleep(1);
            }
        }
        __syncthreads();
        for (int i = tid; i < H; i += 64) hbuf[i] = rnn[t * H + i];
        __syncthreads();
    }

    if (w != 0) return;
    // ---- attention + MLP tail (WG 0 only) ----
    if (tid < T) {
        float s = 0.0f;
        for (int h = 0; h < H; h++) s += rnn[tid * H + h] * Watt[h];
        sc[tid] = tanhf(s + batt[0]);
    }
    __syncthreads();
    if (tid == 0) {
        float m = -1e30f;
        for (int t = 0; t < T; t++) m = fmaxf(m, sc[t]);
        float su = 0.0f;
        for (int t = 0; t < T; t++) { float e = expf(sc[t] - m); attw[t] = e; su += e; }
        float inv = 1.0f / su;
        for (int t = 0; t < T; t++) attw[t] *= inv;
    }
    __syncthreads();
    for (int h = tid; h < H; h += 64) {
        float a = 0.0f;
        for (int t = 0; t < T; t++) a += rnn[t * H + h] * attw[t];
        ctx[h] = a;
    }
    __syncthreads();
    {
        float a = bp1[tid];
        #pragma unroll 8
        for (int h = 0; h < H; h++) a += ctx[h] * Wp1[h * 64 + tid];
        hid[tid] = fmaxf(a, 0.0f);
    }
    __syncthreads();
    if (tid == 0) {
        float r = bp2[0];
        for (int j = 0; j < 64; j++) r += hid[j] * Wp2[j];
        out[0] = (r > 20.0f) ? r : log1pf(expf(r));
    }
}

extern "C" void kernel_launch(void* const* d_in, const int* in_sizes, int n_in,
                              void* d_out, int out_size, void* d_ws, size_t ws_size,
                              hipStream_t stream) {
    const float* x      = (const float*)d_in[0];
    const int*   ei     = (const int*)d_in[1];
    const float* fgate  = (const float*)d_in[2];
    const float* egate  = (const float*)d_in[3];
    const float* cached = (const float*)d_in[4];
    const float* Wproj  = (const float*)d_in[5];
    const float* bproj  = (const float*)d_in[6];
    const float* Wg1    = (const float*)d_in[7];
    const float* bg1    = (const float*)d_in[8];
    const float* Wg2    = (const float*)d_in[9];
    const float* bg2    = (const float*)d_in[10];
    const float* Wih    = (const float*)d_in[11];
    const float* Whh    = (const float*)d_in[12];
    const float* bih    = (const float*)d_in[13];
    const float* bhh    = (const float*)d_in[14];
    const float* Watt   = (const float*)d_in[15];
    const float* batt   = (const float*)d_in[16];
    const float* Wp1    = (const float*)d_in[17];
    const float* bp1    = (const float*)d_in[18];
    const float* Wp2    = (const float*)d_in[19];
    const float* bp2    = (const float*)d_in[20];
    const int*   ptgt   = (const int*)d_in[21];
    const int*   pepos  = (const int*)d_in[22];

    char* ws = (char*)d_ws;
    float* deg   = (float*)(ws + OFF_DEG);
    int*   cnt   = (int*)(ws + OFF_CNT);
    unsigned char* fH1 = (unsigned char*)(ws + OFF_FH1);
    unsigned char* fP  = (unsigned char*)(ws + OFF_FP);
    int*   idxP  = (int*)(ws + OFF_IDXP);
    int*   idxH1 = (int*)(ws + OFF_IDXH1);
    int*   srcA  = (int*)(ws + OFF_SRCA);
    float* wA    = (float*)(ws + OFF_WA);
    int*   srcB  = (int*)(ws + OFF_SRCB);
    int*   dstB  = (int*)(ws + OFF_DSTB);
    float* wB    = (float*)(ws + OFF_WB);
    int*   listP = (int*)(ws + OFF_LISTP);
    int*   listH = (int*)(ws + OFF_LISTH);
    float* q     = (float*)(ws + OFF_Q);
    float* h1s   = (float*)(ws + OFF_H1S);
    float* rs    = (float*)(ws + OFF_RS);
    float* emb   = (float*)(ws + OFF_EMB);
    float* seq   = (float*)(ws + OFF_SEQ);
    float* xproj = (float*)(ws + OFF_XPROJ);
    float* rnn   = (float*)(ws + OFF_RNN);

    hipMemsetAsync(ws, 0, ZERO_END, stream);

    k_deg_scan<<<(E + 255) / 256, 256, 0, stream>>>(ei, egate, ptgt, deg, cnt, fH1, srcA, wA);
    k_scan2<<<(E + 255) / 256, 256, 0, stream>>>(ei, egate, fH1, fP, cnt, srcB, dstB, wB);
    k_compact<<<(N + 255) / 256, 256, 0, stream>>>(fH1, fP, cnt, listP, listH, idxP, idxH1);
    k_pq<<<CAPP, 128, 0, stream>>>(x, fgate, Wproj, bproj, Wg1, cnt, listP, q);
    k_h1<<<CAPH, 256, 0, stream>>>(ptgt, deg, cnt, listH, idxP, srcB, dstB, wB, q, bg1, Wg2, h1s, rs, emb);
    k_h2_seq<<<1, 256, 0, stream>>>(ptgt, pepos, deg, cnt, idxH1, srcA, wA, rs, bg2, cached, emb, seq);
    k_xproj<<<T, 1024, 0, stream>>>(seq, Wih, bih, bhh, xproj);
    k_lstm<<<32, 64, 0, stream>>>(Whh, xproj, rnn, cnt + 4, Watt, batt, Wp1, bp1, Wp2, bp2, (float*)d_out);
}

// Round 2
// 268.914 us; speedup vs baseline: 1.2029x; 1.2029x over previous
//
#include <hip/hip_runtime.h>
#include <math.h>

// Problem constants (from reference)
constexpr int N = 50000, E = 800000, F = 512, P = 128, G = 256, H = 256, T = 24;
// Capacity caps (expected: ~16 edges->target, ~290 2-hop edges, ~300 nodes)
constexpr int CAPA = 4096, CAPB = 32768, CAPP = 2048, CAPH = 512;

// Workspace layout (bytes), all 64-aligned
constexpr size_t OFF_DEG   = 0;         // float[N]
constexpr size_t OFF_CNT   = 200704;    // int[16]: 0=cntA,1=cntB,2=cntP,3=cntH
constexpr size_t OFF_FLAGS = 200768;    // int[32*16] barrier flags (64B-padded)
constexpr size_t OFF_FH1   = 202816;    // uchar[N]
constexpr size_t OFF_FP    = 252992;    // uchar[N]
constexpr size_t ZERO_END  = 303168;    // memset [0, ZERO_END)
constexpr size_t OFF_IDXP  = 303168;    // int[N]
constexpr size_t OFF_IDXH1 = 503872;    // int[N]
constexpr size_t OFF_SRCA  = 704576;    // int[CAPA]
constexpr size_t OFF_WA    = 720960;    // float[CAPA]
constexpr size_t OFF_SRCB  = 737344;    // int[CAPB]
constexpr size_t OFF_DSTB  = 868416;    // int[CAPB]
constexpr size_t OFF_WB    = 999488;    // float[CAPB]
constexpr size_t OFF_LISTP = 1130560;   // int[CAPP]
constexpr size_t OFF_LISTH = 1138752;   // int[CAPH]
constexpr size_t OFF_Q     = 1140800;   // float[CAPP*G]
constexpr size_t OFF_H1S   = 3237952;   // float[CAPH*G]
constexpr size_t OFF_RS    = 3762240;   // float[CAPH*G]
constexpr size_t OFF_EMB   = 4286528;   // float[2G]
constexpr size_t OFF_SEQ   = 4288576;   // float[T*2G]
constexpr size_t OFF_XPROJ = 4337728;   // float[T*4H]
constexpr size_t OFF_RNN   = 4436032;   // float[T*H]

__device__ __forceinline__ float sigmoidf_(float x) { return 1.0f / (1.0f + expf(-x)); }

// Pass 1: degree accumulation + collect edges whose dst == target; flag 1-hop srcs.
__global__ void k_deg_scan(const int* __restrict__ ei, const float* __restrict__ eg,
                           const int* __restrict__ ptgt, float* __restrict__ deg,
                           int* __restrict__ cnt, unsigned char* __restrict__ fH1,
                           int* __restrict__ srcA, float* __restrict__ wA) {
    int target = *ptgt;
    int e = blockIdx.x * 256 + threadIdx.x;
    if (e < E) {
        int d = ei[E + e];
        float w = eg[e];
        atomicAdd(&deg[d], w);
        if (d == target) {
            int s = ei[e];
            int slot = atomicAdd(&cnt[0], 1);
            if (slot < CAPA) { srcA[slot] = s; wA[slot] = w; }
            fH1[s] = 1;
        }
    }
    if (blockIdx.x == 0 && threadIdx.x == 0) fH1[target] = 1;
}

// Pass 2: collect edges whose dst is a needed-h1 node; flag their srcs as needing p/q.
__global__ void k_scan2(const int* __restrict__ ei, const float* __restrict__ eg,
                        const unsigned char* __restrict__ fH1, unsigned char* __restrict__ fP,
                        int* __restrict__ cnt, int* __restrict__ srcB,
                        int* __restrict__ dstB, float* __restrict__ wB) {
    int e = blockIdx.x * 256 + threadIdx.x;
    if (e >= E) return;
    int d = ei[E + e];
    if (fH1[d]) {
        int s = ei[e];
        float w = eg[e];
        int slot = atomicAdd(&cnt[1], 1);
        if (slot < CAPB) { srcB[slot] = s; dstB[slot] = d; wB[slot] = w; }
        fP[s] = 1;
    }
}

// Compact flagged node sets into lists with index maps.
__global__ void k_compact(const unsigned char* __restrict__ fH1, const unsigned char* __restrict__ fP,
                          int* __restrict__ cnt, int* __restrict__ listP, int* __restrict__ listH,
                          int* __restrict__ idxP, int* __restrict__ idxH1) {
    int n = blockIdx.x * 256 + threadIdx.x;
    if (n >= N) return;
    if (fH1[n]) {
        int sh = atomicAdd(&cnt[3], 1);
        if (sh < CAPH) listH[sh] = n;
        idxH1[n] = sh;
    }
    if (fP[n] || fH1[n]) {
        int sp = atomicAdd(&cnt[2], 1);
        if (sp < CAPP) listP[sp] = n;
        idxP[n] = sp;
    }
}

// q[n] = relu((x[n]*feat_gate) @ W_proj + b_proj) @ W_g1, 8 nodes per block.
__global__ void k_pq(const float* __restrict__ x, const float* __restrict__ fgate,
                     const float* __restrict__ Wproj, const float* __restrict__ bproj,
                     const float* __restrict__ Wg1, const int* __restrict__ cnt,
                     const int* __restrict__ listP, float* __restrict__ q) {
    __shared__ float xm[8][F];   // 16 KB
    __shared__ float pv[8][P];   // 4 KB
    int nP = min(cnt[2], CAPP);
    int r0 = blockIdx.x * 8;
    if (r0 >= nP) return;
    int nr = min(8, nP - r0);
    int tid = threadIdx.x;  // 256 threads
    for (int i = tid; i < 8 * F; i += 256) {
        int r = i >> 9, k = i & (F - 1);
        xm[r][k] = (r < nr) ? x[(size_t)listP[r0 + r] * F + k] * fgate[k] : 0.0f;
    }
    __syncthreads();
    // stage 1: p tile (8 x 128). thread: col=tid&127, row group tid>>7 -> 4 rows
    int col = tid & 127, rg = (tid >> 7) * 4;
    float ac0 = bproj[col], ac1 = ac0, ac2 = ac0, ac3 = ac0;
    #pragma unroll 4
    for (int k = 0; k < F; k++) {
        float wv = Wproj[k * P + col];
        ac0 += xm[rg + 0][k] * wv; ac1 += xm[rg + 1][k] * wv;
        ac2 += xm[rg + 2][k] * wv; ac3 += xm[rg + 3][k] * wv;
    }
    pv[rg + 0][col] = fmaxf(ac0, 0.0f); pv[rg + 1][col] = fmaxf(ac1, 0.0f);
    pv[rg + 2][col] = fmaxf(ac2, 0.0f); pv[rg + 3][col] = fmaxf(ac3, 0.0f);
    __syncthreads();
    // stage 2: q tile (8 x 256). thread: col j = tid, 8 rows
    float a[8];
    #pragma unroll
    for (int r = 0; r < 8; r++) a[r] = 0.0f;
    #pragma unroll 4
    for (int k = 0; k < P; k++) {
        float wv = Wg1[k * G + tid];
        #pragma unroll
        for (int r = 0; r < 8; r++) a[r] += pv[r][k] * wv;
    }
    for (int r = 0; r < nr; r++) q[(size_t)(r0 + r) * G + tid] = a[r];
}

// h1 for 1-hop-set nodes, then r = h1 @ W_g2. Also capture h1[target] -> emb[0:256].
__global__ void k_h1(const int* __restrict__ ptgt, const float* __restrict__ deg,
                     const int* __restrict__ cnt, const int* __restrict__ listH,
                     const int* __restrict__ idxP, const int* __restrict__ srcB,
                     const int* __restrict__ dstB, const float* __restrict__ wB,
                     const float* __restrict__ q, const float* __restrict__ bg1,
                     const float* __restrict__ Wg2, float* __restrict__ h1s,
                     float* __restrict__ rs, float* __restrict__ emb) {
    __shared__ float h1row[G];
    int b = blockIdx.x;
    int nH = min(cnt[3], CAPH);
    if (b >= nH) return;
    int n = listH[b];
    int target = *ptgt;
    int g = threadIdx.x;  // 256 threads
    float dn = 1.0f / sqrtf(deg[n] + 1.0f);
    float acc = bg1[g] + q[(size_t)idxP[n] * G + g] * dn * dn;
    int nB = min(cnt[1], CAPB);
    for (int e = 0; e < nB; e++) {
        if (dstB[e] == n) {
            int s = srcB[e];
            float nm = (1.0f / sqrtf(deg[s] + 1.0f)) * wB[e] * dn;
            acc += nm * q[(size_t)idxP[s] * G + g];
        }
    }
    float hv = fmaxf(acc, 0.0f);
    h1row[g] = hv;
    h1s[(size_t)b * G + g] = hv;
    if (n == target) emb[g] = hv;
    __syncthreads();
    float r = 0.0f;
    #pragma unroll 8
    for (int k = 0; k < G; k++) r += h1row[k] * Wg2[k * G + g];
    rs[(size_t)b * G + g] = r;
}

// h2[target], emb[256:512], and build seq (cached_gcn with row explain_pos replaced).
__global__ void k_h2_seq(const int* __restrict__ ptgt, const int* __restrict__ pepos,
                         const float* __restrict__ deg, const int* __restrict__ cnt,
                         const int* __restrict__ idxH1, const int* __restrict__ srcA,
                         const float* __restrict__ wA, const float* __restrict__ rs,
                         const float* __restrict__ bg2, const float* __restrict__ cached,
                         float* __restrict__ emb, float* __restrict__ seq) {
    int target = *ptgt;
    int epos = *pepos;
    int g = threadIdx.x;  // 256 threads
    float dt = 1.0f / sqrtf(deg[target] + 1.0f);
    int it = idxH1[target];
    float acc = bg2[g] + rs[(size_t)it * G + g] * dt * dt;
    int nA = min(cnt[0], CAPA);
    for (int e = 0; e < nA; e++) {
        int s = srcA[e];
        acc += (1.0f / sqrtf(deg[s] + 1.0f)) * wA[e] * dt * rs[(size_t)idxH1[s] * G + g];
    }
    emb[G + g] = fmaxf(acc, 0.0f);
    __syncthreads();
    for (int i = g; i < T * 2 * G; i += 256) {
        int t = i >> 9, k = i & 511;
        seq[i] = (t == epos) ? emb[k] : cached[i];
    }
}

// xproj[t][j] = seq[t] @ W_ih[:,j] + b_ih[j] + b_hh[j]
// 16 blocks x 256 threads; block owns 64 columns, all T rows. W_ih read exactly once.
__global__ void k_xproj(const float* __restrict__ seq, const float* __restrict__ Wih,
                        const float* __restrict__ bih, const float* __restrict__ bhh,
                        float* __restrict__ xproj) {
    __shared__ float s[T][2 * G];  // 49 KB
    int tid = threadIdx.x;
    for (int i = tid; i < T * 2 * G; i += 256) s[i >> 9][i & 511] = seq[i];
    __syncthreads();
    int col = blockIdx.x * 64 + (tid & 63);
    int tg = tid >> 6;  // 0..3
    float base = bih[col] + bhh[col];
    float acc[6];
    #pragma unroll
    for (int i = 0; i < 6; i++) acc[i] = base;
    #pragma unroll 4
    for (int k = 0; k < 2 * G; k++) {
        float wv = Wih[k * 4 * H + col];
        #pragma unroll
        for (int i = 0; i < 6; i++) acc[i] += s[tg + i * 4][k] * wv;
    }
    #pragma unroll
    for (int i = 0; i < 6; i++) xproj[(tg + i * 4) * 4 * H + col] = acc[i];
}

// Sequential LSTM over 32 WGs x 1 wave. Each WG owns 8 hidden channels (32 gate
// columns); each thread keeps its 128-row W_hh column-half in VGPRs.
// Cross-WG sync: per-WG padded flag line (release store) + 32-lane parallel poll.
__global__ __launch_bounds__(64) void k_lstm(
        const float* __restrict__ Whh, const float* __restrict__ xproj,
        float* __restrict__ rnn, int* __restrict__ flags,
        const float* __restrict__ Watt, const float* __restrict__ batt,
        const float* __restrict__ Wp1, const float* __restrict__ bp1,
        const float* __restrict__ Wp2, const float* __restrict__ bp2,
        float* __restrict__ out) {
    __shared__ float hbuf[H];
    __shared__ float gt[32];
    __shared__ float sc[T];
    __shared__ float attw[T];
    __shared__ float ctx[H];
    __shared__ float hid[64];

    int w = blockIdx.x;        // 0..31
    int tid = threadIdx.x;     // 0..63 (one wave)
    int c = tid & 31;          // local gate-column 0..31
    int kh = tid >> 5;         // k-half 0/1
    int colg = (c >> 3) * H + w * 8 + (c & 7);  // global gate column
    int k0 = kh * 128;

    // Preload this thread's W_hh column-half into registers (reused all T steps).
    float wreg[128];
    #pragma unroll
    for (int k = 0; k < 128; k++) wreg[k] = Whh[(size_t)(k0 + k) * 4 * H + colg];

    for (int i = tid; i < H; i += 64) hbuf[i] = 0.0f;
    float cstate = 0.0f;  // live in lanes 0..7
    __syncthreads();

    for (int t = 0; t < T; t++) {
        float a = 0.0f;
        #pragma unroll
        for (int kk = 0; kk < 32; kk++) {
            float4 hv = *(const float4*)&hbuf[k0 + kk * 4];
            a += hv.x * wreg[kk * 4] + hv.y * wreg[kk * 4 + 1]
               + hv.z * wreg[kk * 4 + 2] + hv.w * wreg[kk * 4 + 3];
        }
        a += __shfl_xor(a, 32);  // combine k-halves; lanes 0..31 now hold full dot
        float g = a + xproj[t * 4 * H + colg];
        if (tid < 32) gt[tid] = g;
        __syncthreads();
        if (tid < 8) {
            float ig = sigmoidf_(gt[tid]);
            float fg = sigmoidf_(gt[8 + tid]);
            float gg = tanhf(gt[16 + tid]);
            float og = sigmoidf_(gt[24 + tid]);
            cstate = fg * cstate + ig * gg;
            rnn[t * H + w * 8 + tid] = og * tanhf(cstate);
        }
        __syncthreads();
        if (tid == 0)
            __hip_atomic_store(&flags[w * 16], t + 1, __ATOMIC_RELEASE, __HIP_MEMORY_SCOPE_AGENT);
        int need = t + 1;
        int v = need;
        do {
            if (tid < 32)
                v = __hip_atomic_load(&flags[tid * 16], __ATOMIC_ACQUIRE, __HIP_MEMORY_SCOPE_AGENT);
        } while (!__all(v >= need));
        for (int i = tid; i < H; i += 64) hbuf[i] = rnn[t * H + i];
        __syncthreads();
    }

    if (w != 0) return;
    // ---- attention + MLP tail (WG 0 only) ----
    if (tid < T) {
        float s = 0.0f;
        for (int h = 0; h < H; h++) s += rnn[tid * H + h] * Watt[h];
        sc[tid] = tanhf(s + batt[0]);
    }
    __syncthreads();
    if (tid == 0) {
        float m = -1e30f;
        for (int t = 0; t < T; t++) m = fmaxf(m, sc[t]);
        float su = 0.0f;
        for (int t = 0; t < T; t++) { float e = expf(sc[t] - m); attw[t] = e; su += e; }
        float inv = 1.0f / su;
        for (int t = 0; t < T; t++) attw[t] *= inv;
    }
    __syncthreads();
    for (int h = tid; h < H; h += 64) {
        float a = 0.0f;
        for (int t = 0; t < T; t++) a += rnn[t * H + h] * attw[t];
        ctx[h] = a;
    }
    __syncthreads();
    {
        float a = bp1[tid];
        #pragma unroll 8
        for (int h = 0; h < H; h++) a += ctx[h] * Wp1[h * 64 + tid];
        hid[tid] = fmaxf(a, 0.0f);
    }
    __syncthreads();
    if (tid == 0) {
        float r = bp2[0];
        for (int j = 0; j < 64; j++) r += hid[j] * Wp2[j];
        out[0] = (r > 20.0f) ? r : log1pf(expf(r));
    }
}

extern "C" void kernel_launch(void* const* d_in, const int* in_sizes, int n_in,
                              void* d_out, int out_size, void* d_ws, size_t ws_size,
                              hipStream_t stream) {
    const float* x      = (const float*)d_in[0];
    const int*   ei     = (const int*)d_in[1];
    const float* fgate  = (const float*)d_in[2];
    const float* egate  = (const float*)d_in[3];
    const float* cached = (const float*)d_in[4];
    const float* Wproj  = (const float*)d_in[5];
    const float* bproj  = (const float*)d_in[6];
    const float* Wg1    = (const float*)d_in[7];
    const float* bg1    = (const float*)d_in[8];
    const float* Wg2    = (const float*)d_in[9];
    const float* bg2    = (const float*)d_in[10];
    const float* Wih    = (const float*)d_in[11];
    const float* Whh    = (const float*)d_in[12];
    const float* bih    = (const float*)d_in[13];
    const float* bhh    = (const float*)d_in[14];
    const float* Watt   = (const float*)d_in[15];
    const float* batt   = (const float*)d_in[16];
    const float* Wp1    = (const float*)d_in[17];
    const float* bp1    = (const float*)d_in[18];
    const float* Wp2    = (const float*)d_in[19];
    const float* bp2    = (const float*)d_in[20];
    const int*   ptgt   = (const int*)d_in[21];
    const int*   pepos  = (const int*)d_in[22];

    char* ws = (char*)d_ws;
    float* deg   = (float*)(ws + OFF_DEG);
    int*   cnt   = (int*)(ws + OFF_CNT);
    int*   flags = (int*)(ws + OFF_FLAGS);
    unsigned char* fH1 = (unsigned char*)(ws + OFF_FH1);
    unsigned char* fP  = (unsigned char*)(ws + OFF_FP);
    int*   idxP  = (int*)(ws + OFF_IDXP);
    int*   idxH1 = (int*)(ws + OFF_IDXH1);
    int*   srcA  = (int*)(ws + OFF_SRCA);
    float* wA    = (float*)(ws + OFF_WA);
    int*   srcB  = (int*)(ws + OFF_SRCB);
    int*   dstB  = (int*)(ws + OFF_DSTB);
    float* wB    = (float*)(ws + OFF_WB);
    int*   listP = (int*)(ws + OFF_LISTP);
    int*   listH = (int*)(ws + OFF_LISTH);
    float* q     = (float*)(ws + OFF_Q);
    float* h1s   = (float*)(ws + OFF_H1S);
    float* rs    = (float*)(ws + OFF_RS);
    float* emb   = (float*)(ws + OFF_EMB);
    float* seq   = (float*)(ws + OFF_SEQ);
    float* xproj = (float*)(ws + OFF_XPROJ);
    float* rnn   = (float*)(ws + OFF_RNN);

    hipMemsetAsync(ws, 0, ZERO_END, stream);

    k_deg_scan<<<(E + 255) / 256, 256, 0, stream>>>(ei, egate, ptgt, deg, cnt, fH1, srcA, wA);
    k_scan2<<<(E + 255) / 256, 256, 0, stream>>>(ei, egate, fH1, fP, cnt, srcB, dstB, wB);
    k_compact<<<(N + 255) / 256, 256, 0, stream>>>(fH1, fP, cnt, listP, listH, idxP, idxH1);
    k_pq<<<CAPP / 8, 256, 0, stream>>>(x, fgate, Wproj, bproj, Wg1, cnt, listP, q);
    k_h1<<<CAPH, 256, 0, stream>>>(ptgt, deg, cnt, listH, idxP, srcB, dstB, wB, q, bg1, Wg2, h1s, rs, emb);
    k_h2_seq<<<1, 256, 0, stream>>>(ptgt, pepos, deg, cnt, idxH1, srcA, wA, rs, bg2, cached, emb, seq);
    k_xproj<<<16, 256, 0, stream>>>(seq, Wih, bih, bhh, xproj);
    k_lstm<<<32, 64, 0, stream>>>(Whh, xproj, rnn, flags, Watt, batt, Wp1, bp1, Wp2, bp2, (float*)d_out);
}

// Round 3
// 220.966 us; speedup vs baseline: 1.4639x; 1.2170x over previous
//
#include <hip/hip_runtime.h>
#include <math.h>

// Problem constants (from reference)
constexpr int N = 50000, E = 800000, F = 512, P = 128, G = 256, H = 256, T = 24;
// Capacity caps (expected: ~16 edges->target, ~290 2-hop edges, ~300 nodes)
constexpr int CAPA = 4096, CAPB = 32768, CAPP = 2048, CAPH = 512;

// Workspace layout (bytes), 64-aligned
constexpr size_t OFF_DEG   = 0;        // float[N]
constexpr size_t OFF_CNT   = 200704;   // int[16]: 0=cntA,1=cntB,2=cntP,3=cntH
constexpr size_t OFF_COMM  = 200768;   // ull[2][256] tagged h-words (ping-pong)
constexpr size_t OFF_FH1   = 204864;   // uchar[N]
constexpr size_t OFF_FP    = 254912;   // uchar[N]
constexpr size_t ZERO_END  = 304960;   // memset [0, ZERO_END)
constexpr size_t OFF_IDXP  = 304960;   // int[N]
constexpr size_t OFF_IDXH1 = 504960;   // int[N]
constexpr size_t OFF_SRCA  = 704960;   // int[CAPA]
constexpr size_t OFF_WA    = 721344;   // float[CAPA]
constexpr size_t OFF_SRCB  = 737728;   // int[CAPB]
constexpr size_t OFF_DSTB  = 868800;   // int[CAPB]
constexpr size_t OFF_WB    = 999872;   // float[CAPB]
constexpr size_t OFF_LISTP = 1130944;  // int[CAPP]
constexpr size_t OFF_LISTH = 1139136;  // int[CAPH]
constexpr size_t OFF_Q     = 1141184;  // float[CAPP*G]
constexpr size_t OFF_RS    = 3238336;  // float[CAPH*G]
constexpr size_t OFF_EMB   = 3762624;  // float[2G]
constexpr size_t OFF_XPROJ = 3764672;  // float[T*4H]

__device__ __forceinline__ float sigmoidf_(float x) { return 1.0f / (1.0f + expf(-x)); }

// Pass 1: degree accumulation + collect edges whose dst == target; flag 1-hop srcs.
__global__ void k_deg_scan(const int* __restrict__ ei, const float* __restrict__ eg,
                           const int* __restrict__ ptgt, float* __restrict__ deg,
                           int* __restrict__ cnt, unsigned char* __restrict__ fH1,
                           int* __restrict__ srcA, float* __restrict__ wA) {
    int target = *ptgt;
    int e = blockIdx.x * 256 + threadIdx.x;
    if (e < E) {
        int d = ei[E + e];
        float w = eg[e];
        atomicAdd(&deg[d], w);
        if (d == target) {
            int s = ei[e];
            int slot = atomicAdd(&cnt[0], 1);
            if (slot < CAPA) { srcA[slot] = s; wA[slot] = w; }
            fH1[s] = 1;
        }
    }
    if (blockIdx.x == 0 && threadIdx.x == 0) fH1[target] = 1;
}

// Pass 2: collect edges whose dst is a needed-h1 node; flag their srcs as needing p/q.
__global__ void k_scan2(const int* __restrict__ ei, const float* __restrict__ eg,
                        const unsigned char* __restrict__ fH1, unsigned char* __restrict__ fP,
                        int* __restrict__ cnt, int* __restrict__ srcB,
                        int* __restrict__ dstB, float* __restrict__ wB) {
    int e = blockIdx.x * 256 + threadIdx.x;
    if (e >= E) return;
    int d = ei[E + e];
    if (fH1[d]) {
        int s = ei[e];
        float w = eg[e];
        int slot = atomicAdd(&cnt[1], 1);
        if (slot < CAPB) { srcB[slot] = s; dstB[slot] = d; wB[slot] = w; }
        fP[s] = 1;
    }
}

// Compact flagged node sets into lists with index maps.
__global__ void k_compact(const unsigned char* __restrict__ fH1, const unsigned char* __restrict__ fP,
                          int* __restrict__ cnt, int* __restrict__ listP, int* __restrict__ listH,
                          int* __restrict__ idxP, int* __restrict__ idxH1) {
    int n = blockIdx.x * 256 + threadIdx.x;
    if (n >= N) return;
    if (fH1[n]) {
        int sh = atomicAdd(&cnt[3], 1);
        if (sh < CAPH) listH[sh] = n;
        idxH1[n] = sh;
    }
    if (fP[n] || fH1[n]) {
        int sp = atomicAdd(&cnt[2], 1);
        if (sp < CAPP) listP[sp] = n;
        idxP[n] = sp;
    }
}

// q[n] = relu((x[n]*feat_gate) @ W_proj + b_proj) @ W_g1, 8 nodes per block.
__global__ void k_pq(const float* __restrict__ x, const float* __restrict__ fgate,
                     const float* __restrict__ Wproj, const float* __restrict__ bproj,
                     const float* __restrict__ Wg1, const int* __restrict__ cnt,
                     const int* __restrict__ listP, float* __restrict__ q) {
    __shared__ float xm[8][F];   // 16 KB
    __shared__ float pv[8][P];   // 4 KB
    int nP = min(cnt[2], CAPP);
    int r0 = blockIdx.x * 8;
    if (r0 >= nP) return;
    int nr = min(8, nP - r0);
    int tid = threadIdx.x;  // 256 threads
    for (int i = tid; i < 8 * F; i += 256) {
        int r = i >> 9, k = i & (F - 1);
        xm[r][k] = (r < nr) ? x[(size_t)listP[r0 + r] * F + k] * fgate[k] : 0.0f;
    }
    __syncthreads();
    int col = tid & 127, rg = (tid >> 7) * 4;
    float ac0 = bproj[col], ac1 = ac0, ac2 = ac0, ac3 = ac0;
    #pragma unroll 4
    for (int k = 0; k < F; k++) {
        float wv = Wproj[k * P + col];
        ac0 += xm[rg + 0][k] * wv; ac1 += xm[rg + 1][k] * wv;
        ac2 += xm[rg + 2][k] * wv; ac3 += xm[rg + 3][k] * wv;
    }
    pv[rg + 0][col] = fmaxf(ac0, 0.0f); pv[rg + 1][col] = fmaxf(ac1, 0.0f);
    pv[rg + 2][col] = fmaxf(ac2, 0.0f); pv[rg + 3][col] = fmaxf(ac3, 0.0f);
    __syncthreads();
    float a[8];
    #pragma unroll
    for (int r = 0; r < 8; r++) a[r] = 0.0f;
    #pragma unroll 4
    for (int k = 0; k < P; k++) {
        float wv = Wg1[k * G + tid];
        #pragma unroll
        for (int r = 0; r < 8; r++) a[r] += pv[r][k] * wv;
    }
    for (int r = 0; r < nr; r++) q[(size_t)(r0 + r) * G + tid] = a[r];
}

// h1 for 1-hop-set nodes, then r = h1 @ W_g2. Also capture h1[target] -> emb[0:256].
__global__ void k_h1(const int* __restrict__ ptgt, const float* __restrict__ deg,
                     const int* __restrict__ cnt, const int* __restrict__ listH,
                     const int* __restrict__ idxP, const int* __restrict__ srcB,
                     const int* __restrict__ dstB, const float* __restrict__ wB,
                     const float* __restrict__ q, const float* __restrict__ bg1,
                     const float* __restrict__ Wg2,
                     float* __restrict__ rs, float* __restrict__ emb) {
    __shared__ float h1row[G];
    int b = blockIdx.x;
    int nH = min(cnt[3], CAPH);
    if (b >= nH) return;
    int n = listH[b];
    int target = *ptgt;
    int g = threadIdx.x;  // 256 threads
    float dn = 1.0f / sqrtf(deg[n] + 1.0f);
    float acc = bg1[g] + q[(size_t)idxP[n] * G + g] * dn * dn;
    int nB = min(cnt[1], CAPB);
    for (int e = 0; e < nB; e++) {
        if (dstB[e] == n) {
            int s = srcB[e];
            float nm = (1.0f / sqrtf(deg[s] + 1.0f)) * wB[e] * dn;
            acc += nm * q[(size_t)idxP[s] * G + g];
        }
    }
    float hv = fmaxf(acc, 0.0f);
    h1row[g] = hv;
    if (n == target) emb[g] = hv;
    __syncthreads();
    float r = 0.0f;
    #pragma unroll 8
    for (int k = 0; k < G; k++) r += h1row[k] * Wg2[k * G + g];
    rs[(size_t)b * G + g] = r;
}

// h2[target] -> emb[256:512].
__global__ void k_h2(const int* __restrict__ ptgt, const float* __restrict__ deg,
                     const int* __restrict__ cnt, const int* __restrict__ idxH1,
                     const int* __restrict__ srcA, const float* __restrict__ wA,
                     const float* __restrict__ rs, const float* __restrict__ bg2,
                     float* __restrict__ emb) {
    int target = *ptgt;
    int g = threadIdx.x;  // 256 threads
    float dt = 1.0f / sqrtf(deg[target] + 1.0f);
    int it = idxH1[target];
    float acc = bg2[g] + rs[(size_t)it * G + g] * dt * dt;
    int nA = min(cnt[0], CAPA);
    for (int e = 0; e < nA; e++) {
        int s = srcA[e];
        acc += (1.0f / sqrtf(deg[s] + 1.0f)) * wA[e] * dt * rs[(size_t)idxH1[s] * G + g];
    }
    emb[G + g] = fmaxf(acc, 0.0f);
}

// xproj[t][j] = seq[t] @ W_ih[:,j] + b_ih[j] + b_hh[j], seq built in-LDS from cached+emb.
// 16 blocks x 256 threads; block owns 64 columns, all T rows. W_ih read exactly once.
__global__ void k_xproj(const float* __restrict__ cached, const float* __restrict__ emb,
                        const int* __restrict__ pepos, const float* __restrict__ Wih,
                        const float* __restrict__ bih, const float* __restrict__ bhh,
                        float* __restrict__ xproj) {
    __shared__ float s[T][2 * G];  // 48 KB
    int tid = threadIdx.x;
    int epos = *pepos;
    for (int i = tid; i < T * 2 * G; i += 256) {
        int t = i >> 9, k = i & 511;
        s[t][k] = (t == epos) ? emb[k] : cached[i];
    }
    __syncthreads();
    int col = blockIdx.x * 64 + (tid & 63);
    int tg = tid >> 6;  // 0..3
    float base = bih[col] + bhh[col];
    float acc[6];
    #pragma unroll
    for (int i = 0; i < 6; i++) acc[i] = base;
    #pragma unroll 4
    for (int k = 0; k < 2 * G; k++) {
        float wv = Wih[k * 4 * H + col];
        #pragma unroll
        for (int i = 0; i < 6; i++) acc[i] += s[tg + i * 4][k] * wv;
    }
    #pragma unroll
    for (int i = 0; i < 6; i++) xproj[(tg + i * 4) * 4 * H + col] = acc[i];
}

// Sequential LSTM over 32 WGs x 1 wave. Each WG owns 8 hidden channels (32 gate
// columns); W_hh column-halves live in VGPRs; xproj prefetched to registers.
// Cross-WG exchange: self-validating (float,tag) 64-bit relaxed agent atomics in a
// ping-pong buffer — no release/acquire (no wbl2/inv), the tag match IS the barrier.
__global__ __launch_bounds__(64) void k_lstm(
        const float* __restrict__ Whh, const float* __restrict__ xproj,
        unsigned long long* __restrict__ comm,
        const float* __restrict__ Watt, const float* __restrict__ batt,
        const float* __restrict__ Wp1, const float* __restrict__ bp1,
        const float* __restrict__ Wp2, const float* __restrict__ bp2,
        float* __restrict__ out) {
    __shared__ float hbuf[H];
    __shared__ float rnn_lds[T][H];  // 24 KB, used by WG0 tail
    __shared__ float sc[T];
    __shared__ float attw[T];
    __shared__ float ctx[H];
    __shared__ float hid[64];

    int w = blockIdx.x;        // 0..31
    int tid = threadIdx.x;     // 0..63 (one wave)
    int c = tid & 31;          // gate-column 0..31 (duplicated across k-halves)
    int kh = tid >> 5;         // k-half 0/1
    int colg = (c >> 3) * H + w * 8 + (c & 7);  // global gate column
    int k0 = kh * 128;

    // Preload W_hh column-half (128 VGPRs) and xproj column (24 VGPRs).
    float wreg[128];
    #pragma unroll
    for (int k = 0; k < 128; k++) wreg[k] = Whh[(size_t)(k0 + k) * 4 * H + colg];
    float xcol[T];
    #pragma unroll
    for (int t = 0; t < T; t++) xcol[t] = xproj[t * 4 * H + colg];

    for (int i = tid; i < H; i += 64) hbuf[i] = 0.0f;
    float cstate = 0.0f;  // live in lanes 0..7
    __syncthreads();

    for (int t = 0; t < T; t++) {
        // dot over this thread's k-half
        float a = 0.0f;
        #pragma unroll
        for (int kk = 0; kk < 32; kk++) {
            float4 hv4 = *(const float4*)&hbuf[k0 + kk * 4];
            a += hv4.x * wreg[kk * 4] + hv4.y * wreg[kk * 4 + 1]
               + hv4.z * wreg[kk * 4 + 2] + hv4.w * wreg[kk * 4 + 3];
        }
        a += __shfl_xor(a, 32);      // every lane: full dot for col (tid&31)
        float g = a + xcol[t];
        // gate exchange via shuffles (lane j<8 gets cols j, 8+j, 16+j, 24+j)
        float gi = __shfl(g, (tid & 7));
        float gf = __shfl(g, 8 + (tid & 7));
        float gg = __shfl(g, 16 + (tid & 7));
        float go = __shfl(g, 24 + (tid & 7));
        int s = t + 1;
        if (tid < 8) {
            cstate = sigmoidf_(gf) * cstate + sigmoidf_(gi) * tanhf(gg);
            float hv = sigmoidf_(go) * tanhf(cstate);
            unsigned long long word =
                ((unsigned long long)__float_as_uint(hv) << 32) | (unsigned)s;
            __hip_atomic_store(&comm[(size_t)(s & 1) * 256 + w * 8 + tid], word,
                               __ATOMIC_RELAXED, __HIP_MEMORY_SCOPE_AGENT);
        }
        // poll+gather: 4 tagged words per lane (channels tid, tid+64, tid+128, tid+192)
        const unsigned long long* cb = comm + (size_t)(s & 1) * 256;
        unsigned long long w0, w1, w2, w3;
        for (;;) {
            w0 = __hip_atomic_load(&cb[tid],       __ATOMIC_RELAXED, __HIP_MEMORY_SCOPE_AGENT);
            w1 = __hip_atomic_load(&cb[tid + 64],  __ATOMIC_RELAXED, __HIP_MEMORY_SCOPE_AGENT);
            w2 = __hip_atomic_load(&cb[tid + 128], __ATOMIC_RELAXED, __HIP_MEMORY_SCOPE_AGENT);
            w3 = __hip_atomic_load(&cb[tid + 192], __ATOMIC_RELAXED, __HIP_MEMORY_SCOPE_AGENT);
            bool ok = ((unsigned)w0 == (unsigned)s) && ((unsigned)w1 == (unsigned)s)
                   && ((unsigned)w2 == (unsigned)s) && ((unsigned)w3 == (unsigned)s);
            if (__all(ok)) break;
        }
        float h0 = __uint_as_float((unsigned)(w0 >> 32));
        float h1 = __uint_as_float((unsigned)(w1 >> 32));
        float h2 = __uint_as_float((unsigned)(w2 >> 32));
        float h3 = __uint_as_float((unsigned)(w3 >> 32));
        hbuf[tid] = h0; hbuf[tid + 64] = h1; hbuf[tid + 128] = h2; hbuf[tid + 192] = h3;
        if (w == 0) {
            rnn_lds[t][tid] = h0; rnn_lds[t][tid + 64] = h1;
            rnn_lds[t][tid + 128] = h2; rnn_lds[t][tid + 192] = h3;
        }
        __syncthreads();
    }

    if (w != 0) return;
    // ---- attention + MLP tail (WG 0 only) ----
    if (tid < T) {
        float sv = 0.0f;
        for (int h = 0; h < H; h++) sv += rnn_lds[tid][h] * Watt[h];
        sc[tid] = tanhf(sv + batt[0]);
    }
    __syncthreads();
    if (tid == 0) {
        float m = -1e30f;
        for (int t = 0; t < T; t++) m = fmaxf(m, sc[t]);
        float su = 0.0f;
        for (int t = 0; t < T; t++) { float e = expf(sc[t] - m); attw[t] = e; su += e; }
        float inv = 1.0f / su;
        for (int t = 0; t < T; t++) attw[t] *= inv;
    }
    __syncthreads();
    for (int h = tid; h < H; h += 64) {
        float a = 0.0f;
        for (int t = 0; t < T; t++) a += rnn_lds[t][h] * attw[t];
        ctx[h] = a;
    }
    __syncthreads();
    {
        float a = bp1[tid];
        #pragma unroll 8
        for (int h = 0; h < H; h++) a += ctx[h] * Wp1[h * 64 + tid];
        hid[tid] = fmaxf(a, 0.0f);
    }
    __syncthreads();
    if (tid == 0) {
        float r = bp2[0];
        for (int j = 0; j < 64; j++) r += hid[j] * Wp2[j];
        out[0] = (r > 20.0f) ? r : log1pf(expf(r));
    }
}

extern "C" void kernel_launch(void* const* d_in, const int* in_sizes, int n_in,
                              void* d_out, int out_size, void* d_ws, size_t ws_size,
                              hipStream_t stream) {
    const float* x      = (const float*)d_in[0];
    const int*   ei     = (const int*)d_in[1];
    const float* fgate  = (const float*)d_in[2];
    const float* egate  = (const float*)d_in[3];
    const float* cached = (const float*)d_in[4];
    const float* Wproj  = (const float*)d_in[5];
    const float* bproj  = (const float*)d_in[6];
    const float* Wg1    = (const float*)d_in[7];
    const float* bg1    = (const float*)d_in[8];
    const float* Wg2    = (const float*)d_in[9];
    const float* bg2    = (const float*)d_in[10];
    const float* Wih    = (const float*)d_in[11];
    const float* Whh    = (const float*)d_in[12];
    const float* bih    = (const float*)d_in[13];
    const float* bhh    = (const float*)d_in[14];
    const float* Watt   = (const float*)d_in[15];
    const float* batt   = (const float*)d_in[16];
    const float* Wp1    = (const float*)d_in[17];
    const float* bp1    = (const float*)d_in[18];
    const float* Wp2    = (const float*)d_in[19];
    const float* bp2    = (const float*)d_in[20];
    const int*   ptgt   = (const int*)d_in[21];
    const int*   pepos  = (const int*)d_in[22];

    char* ws = (char*)d_ws;
    float* deg   = (float*)(ws + OFF_DEG);
    int*   cnt   = (int*)(ws + OFF_CNT);
    unsigned long long* comm = (unsigned long long*)(ws + OFF_COMM);
    unsigned char* fH1 = (unsigned char*)(ws + OFF_FH1);
    unsigned char* fP  = (unsigned char*)(ws + OFF_FP);
    int*   idxP  = (int*)(ws + OFF_IDXP);
    int*   idxH1 = (int*)(ws + OFF_IDXH1);
    int*   srcA  = (int*)(ws + OFF_SRCA);
    float* wA    = (float*)(ws + OFF_WA);
    int*   srcB  = (int*)(ws + OFF_SRCB);
    int*   dstB  = (int*)(ws + OFF_DSTB);
    float* wB    = (float*)(ws + OFF_WB);
    int*   listP = (int*)(ws + OFF_LISTP);
    int*   listH = (int*)(ws + OFF_LISTH);
    float* q     = (float*)(ws + OFF_Q);
    float* rs    = (float*)(ws + OFF_RS);
    float* emb   = (float*)(ws + OFF_EMB);
    float* xproj = (float*)(ws + OFF_XPROJ);

    hipMemsetAsync(ws, 0, ZERO_END, stream);

    k_deg_scan<<<(E + 255) / 256, 256, 0, stream>>>(ei, egate, ptgt, deg, cnt, fH1, srcA, wA);
    k_scan2<<<(E + 255) / 256, 256, 0, stream>>>(ei, egate, fH1, fP, cnt, srcB, dstB, wB);
    k_compact<<<(N + 255) / 256, 256, 0, stream>>>(fH1, fP, cnt, listP, listH, idxP, idxH1);
    k_pq<<<CAPP / 8, 256, 0, stream>>>(x, fgate, Wproj, bproj, Wg1, cnt, listP, q);
    k_h1<<<CAPH, 256, 0, stream>>>(ptgt, deg, cnt, listH, idxP, srcB, dstB, wB, q, bg1, Wg2, rs, emb);
    k_h2<<<1, 256, 0, stream>>>(ptgt, deg, cnt, idxH1, srcA, wA, rs, bg2, emb);
    k_xproj<<<16, 256, 0, stream>>>(cached, emb, pepos, Wih, bih, bhh, xproj);
    k_lstm<<<32, 64, 0, stream>>>(Whh, xproj, comm, Watt, batt, Wp1, bp1, Wp2, bp2, (float*)d_out);
}